// Round 1
// 395.744 us; speedup vs baseline: 1.0120x; 1.0120x over previous
//
#include <hip/hip_runtime.h>

// Problem constants (from setup_inputs): b=4, h=128, w=512, c=128, num_splits=8
#define BH      512   // b*h
#define W_ROWS  512   // w
#define C_DIM   128   // c
#define NSPLIT  8
#define WIN     64
#define SHIFT   32    // win/2

typedef __attribute__((ext_vector_type(8))) short  short8;
typedef __attribute__((ext_vector_type(4))) float  floatx4;

__device__ __forceinline__ ushort f2bf(float x) {
    union { float f; unsigned u; } c; c.f = x;
    unsigned u = c.u;
    return (ushort)((u + 0x7FFFu + ((u >> 16) & 1u)) >> 16);  // RNE
}

// One block per (bh, split) window: 64 queries x 64 keys x 128 channels.
// 4 waves; wave wv owns query rows [16*wv, 16*wv+16).
//
// LDS budget 35840 B -> 4 blocks/CU (was 45056 -> 3 blocks/CU):
//   sK  [64][136] ushort = 17408 B  (272B row stride: QK^T b128 reads at 8-phase floor)
//   sVt flat 128 rows x 144B = 18432 B, 16B-chunk XOR swizzle (chunk ^= (ch>>2)&7):
//        both the b128 transpose-writes and PV b128 reads land on the 8-phase floor
//   sP aliased onto sK (sK is dead after QK^T; extra barrier covers the WAR hazard)
__global__ __launch_bounds__(256, 4)
void swin_attn_kernel(const float* __restrict__ qg,
                      const float* __restrict__ kg,
                      const float* __restrict__ vg,
                      const float* __restrict__ mg,
                      float* __restrict__ og)
{
    __shared__ __align__(16) ushort sK[64][136];     // 17408 B
    __shared__ __align__(16) char   sVt[128 * 144];  // 18432 B

    const int tid  = threadIdx.x;
    const int bh   = blockIdx.x >> 3;
    const int s    = blockIdx.x & 7;
    const int wv   = tid >> 6;     // wave 0..3
    const int lane = tid & 63;
    const int l16  = lane & 15;
    const int quad = lane >> 4;

    const size_t base = (size_t)bh * (W_ROWS * C_DIM);

    // ---- staging map: each thread owns 8 CONSECUTIVE key rows x 4 channels ----
    // (consecutive keys let V be written transposed as one 16B chunk per channel)
    const int j  = tid & 31;        // channel group 0..31
    const int h  = tid >> 5;        // key octet 0..7
    const int c0 = j * 4;           // first channel
    const int r0 = h * 8;           // first key row

    // Issue ALL global loads first (8 K + 8 V + 8 Q float4 per thread) so they
    // stay in flight together: this is the MLP the latency-bound profile lacks.
    floatx4 kr[8], vr[8];
    #pragma unroll
    for (int i = 0; i < 8; ++i) {
        const int rg = (s * WIN + r0 + i + SHIFT) & (W_ROWS - 1);
        kr[i] = *(const floatx4*)(kg + base + (size_t)rg * C_DIM + c0);
    }
    #pragma unroll
    for (int i = 0; i < 8; ++i) {
        const int rg = (s * WIN + r0 + i + SHIFT) & (W_ROWS - 1);
        vr[i] = *(const floatx4*)(vg + base + (size_t)rg * C_DIM + c0);
    }
    // Q prefetch (overlaps the staging loads' latency; converted after LDS writes)
    const int qrow = wv * 16 + l16;
    const int rgq  = (s * WIN + qrow + SHIFT) & (W_ROWS - 1);
    const float* qp = qg + base + (size_t)rgq * C_DIM + quad * 8;
    floatx4 qa[4], qb[4];
    #pragma unroll
    for (int kk = 0; kk < 4; ++kk) {
        qa[kk] = *(const floatx4*)(qp + kk * 32);
        qb[kk] = *(const floatx4*)(qp + kk * 32 + 4);
    }

    // ---- K -> LDS row-major (ushort4 writes, at the bank floor) ----
    #pragma unroll
    for (int i = 0; i < 8; ++i) {
        ushort4 kb;
        kb.x = f2bf(kr[i][0]); kb.y = f2bf(kr[i][1]);
        kb.z = f2bf(kr[i][2]); kb.w = f2bf(kr[i][3]);
        *(ushort4*)&sK[r0 + i][c0] = kb;
    }
    // ---- V -> LDS transposed: one swizzled 16B chunk (8 keys) per channel ----
    // was: 32x ds_write_u16 at 16-way conflict; now: 4x ds_write_b128 at floor
    #pragma unroll
    for (int m = 0; m < 4; ++m) {
        short8 col;
        #pragma unroll
        for (int i = 0; i < 8; ++i) col[i] = (short)f2bf(vr[i][m]);
        const int chnk = h ^ (j & 7);   // (ch>>2)&7 with ch = 4j+m
        *(short8*)(sVt + (size_t)(c0 + m) * 144 + chnk * 16) = col;
    }
    // ---- Q fp32 -> bf16 fragments (registers only) ----
    short8 qf[4];
    #pragma unroll
    for (int kk = 0; kk < 4; ++kk) {
        short8 f;
        f[0] = (short)f2bf(qa[kk][0]); f[1] = (short)f2bf(qa[kk][1]);
        f[2] = (short)f2bf(qa[kk][2]); f[3] = (short)f2bf(qa[kk][3]);
        f[4] = (short)f2bf(qb[kk][0]); f[5] = (short)f2bf(qb[kk][1]);
        f[6] = (short)f2bf(qb[kk][2]); f[7] = (short)f2bf(qb[kk][3]);
        qf[kk] = f;
    }
    __syncthreads();

    // ---- QK^T: scores[q][key], per-wave 16x64 strip ----
    floatx4 acc[4];
    const floatx4 fz = {0.f, 0.f, 0.f, 0.f};
    #pragma unroll
    for (int t = 0; t < 4; ++t) acc[t] = fz;

    #pragma unroll
    for (int kk = 0; kk < 4; ++kk) {          // K-dim steps of 32 channels
        const int ch0 = kk * 32 + quad * 8;
        #pragma unroll
        for (int t = 0; t < 4; ++t) {         // key tiles of 16
            short8 bf = *(const short8*)&sK[t * 16 + l16][ch0];
            acc[t] = __builtin_amdgcn_mfma_f32_16x16x32_bf16(qf[kk], bf, acc[t], 0, 0, 0);
        }
    }

    // ---- scale + mask + softmax (fp32, registers only) ----
    // C/D layout: col = lane&15 (+16*t), row = quad*4 + r (+16*wv)
    const float* mrow = mg + s * (WIN * WIN);
    float pr[4][4];                            // [t][r], normalized probs
    #pragma unroll
    for (int r = 0; r < 4; ++r) {
        const int qw = wv * 16 + quad * 4 + r; // window-local query row
        float mx = -3.0e38f;
        #pragma unroll
        for (int t = 0; t < 4; ++t) {
            float val = acc[t][r] * 0.08838834764831845f      // 1/sqrt(128)
                      + mrow[qw * WIN + t * 16 + l16];
            pr[t][r] = val;
            mx = fmaxf(mx, val);
        }
        mx = fmaxf(mx, __shfl_xor(mx, 1));
        mx = fmaxf(mx, __shfl_xor(mx, 2));
        mx = fmaxf(mx, __shfl_xor(mx, 4));
        mx = fmaxf(mx, __shfl_xor(mx, 8));
        float sum = 0.f;
        #pragma unroll
        for (int t = 0; t < 4; ++t) {
            float e = __expf(pr[t][r] - mx);
            pr[t][r] = e;
            sum += e;
        }
        sum += __shfl_xor(sum, 1);
        sum += __shfl_xor(sum, 2);
        sum += __shfl_xor(sum, 4);
        sum += __shfl_xor(sum, 8);
        float rs = 1.0f / sum;
        #pragma unroll
        for (int t = 0; t < 4; ++t) pr[t][r] *= rs;
    }

    // sK is dead from here; reuse its space for P (WAR hazard -> barrier)
    __syncthreads();
    ushort* sP = (ushort*)&sK[0][0];           // [64][72]
    #pragma unroll
    for (int r = 0; r < 4; ++r) {
        const int qw = wv * 16 + quad * 4 + r;
        #pragma unroll
        for (int t = 0; t < 4; ++t)
            sP[qw * 72 + t * 16 + l16] = f2bf(pr[t][r]);
    }
    __syncthreads();

    // ---- PV: out[q][ch] = sum_key P[q][key] * V[key][ch] ----
    floatx4 o[8];
    #pragma unroll
    for (int t = 0; t < 8; ++t) o[t] = fz;
    #pragma unroll
    for (int kk = 0; kk < 2; ++kk) {          // key steps of 32
        short8 pf = *(const short8*)&sP[(wv * 16 + l16) * 72 + kk * 32 + quad * 8];
        #pragma unroll
        for (int t = 0; t < 8; ++t) {         // channel tiles of 16
            const int ch   = t * 16 + l16;
            const int chnk = (kk * 4 + quad) ^ ((ch >> 2) & 7);
            short8 vf = *(const short8*)(sVt + (size_t)ch * 144 + chnk * 16);
            o[t] = __builtin_amdgcn_mfma_f32_16x16x32_bf16(pf, vf, o[t], 0, 0, 0);
        }
    }

    // ---- epilogue: fp32 store with inverse roll ----
    #pragma unroll
    for (int r = 0; r < 4; ++r) {
        const int qw = wv * 16 + quad * 4 + r;
        const int rg = (s * WIN + qw + SHIFT) & (W_ROWS - 1);
        float* op = og + base + (size_t)rg * C_DIM + l16;
        #pragma unroll
        for (int t = 0; t < 8; ++t)
            op[t * 16] = o[t][r];
    }
}

extern "C" void kernel_launch(void* const* d_in, const int* in_sizes, int n_in,
                              void* d_out, int out_size, void* d_ws, size_t ws_size,
                              hipStream_t stream) {
    const float* q = (const float*)d_in[0];
    const float* k = (const float*)d_in[1];
    const float* v = (const float*)d_in[2];
    const float* m = (const float*)d_in[3];
    float* out = (float*)d_out;
    dim3 grid(BH * NSPLIT), block(256);
    hipLaunchKernelGGL(swin_attn_kernel, grid, block, 0, stream, q, k, v, m, out);
}